// Round 6
// baseline (468.419 us; speedup 1.0000x reference)
//
#include <hip/hip_runtime.h>
#include <hip/hip_bf16.h>
#include <math.h>

// Problem constants
constexpr int B  = 16;
constexpr int N  = 8192;     // 2^13
constexpr int E  = 131072;   // 2^17
constexpr int H  = 128;
constexpr int K1 = 4096;
constexpr int K2 = 2048;

constexpr int CHUNKS = 16;         // edge chunks per graph (8192 edges each)
constexpr int NBK    = 16;         // dst buckets (dst>>9, 512 nodes each)
constexpr int FCAP   = 12288;      // final_scatter LDS capacity

typedef __attribute__((ext_vector_type(8))) short short8;
typedef __attribute__((ext_vector_type(4))) float floatx4;

__device__ __forceinline__ unsigned short f2bf(float f) {
  unsigned u = __float_as_uint(f);
  return (unsigned short)((u + 0x7FFFu + ((u >> 16) & 1u)) >> 16);  // RNE
}
__device__ __forceinline__ float bf2f(unsigned short s) {
  return __uint_as_float(((unsigned)s) << 16);
}
__device__ __forceinline__ float rdlane_f(float v, int l) {
  return __uint_as_float((unsigned)__builtin_amdgcn_readlane((int)__float_as_uint(v), l));
}
__device__ __forceinline__ unsigned cvt_pk_bf16(float a, float b) {
  unsigned r;
  asm("v_cvt_pk_bf16_f32 %0, %1, %2" : "=v"(r) : "v"(a), "v"(b));
  return r;
}

// ---------------------------------------------------------------------------
// CSR build (streaming counting sort, R5) — unchanged
// ---------------------------------------------------------------------------
__global__ __launch_bounds__(256) void hist_pass(const int* __restrict__ ei,
                                                 int* __restrict__ bchist) {
  int blk = blockIdx.x;                 // B*CHUNKS = 256
  int b = blk >> 4, c = blk & 15;
  __shared__ int h16[NBK];
  if (threadIdx.x < NBK) h16[threadIdx.x] = 0;
  __syncthreads();
  const int* dstp = ei + (size_t)b * 2 * E + E + c * 8192;
  for (int i = 0; i < 32; ++i) {
    int dst = dstp[i * 256 + threadIdx.x];
    atomicAdd(&h16[dst >> 9], 1);
  }
  __syncthreads();
  if (threadIdx.x < NBK) bchist[(blk << 4) + threadIdx.x] = h16[threadIdx.x];
}

__global__ __launch_bounds__(256) void bucket_scan(const int* __restrict__ bchist,
                                                   int* __restrict__ cursor,
                                                   int* __restrict__ bbase) {
  int b = blockIdx.x;                   // B = 16
  int tid = threadIdx.x;                // 256 = CHUNKS*NBK
  int c = tid >> 4, k = tid & 15;
  __shared__ int arr[CHUNKS][NBK];
  __shared__ int base[NBK + 1];
  arr[c][k] = bchist[((b * CHUNKS + c) << 4) + k];
  __syncthreads();
  if (tid == 0) {
    int run = 0;
    for (int kk = 0; kk < NBK; ++kk) {
      base[kk] = run;
      int t = 0;
      for (int cc = 0; cc < CHUNKS; ++cc) t += arr[cc][kk];
      run += t;
    }
    base[NBK] = run;
  }
  __syncthreads();
  int pre = 0;
  for (int cc = 0; cc < c; ++cc) pre += arr[cc][k];
  cursor[((b * CHUNKS + c) << 4) + k] = base[k] + pre;
  if (tid < NBK + 1) bbase[b * (NBK + 1) + tid] = base[tid];
}

__global__ __launch_bounds__(256) void bin_scatter(const int* __restrict__ ei,
                                                   const int* __restrict__ cursor,
                                                   unsigned* __restrict__ pbuf) {
  int blk = blockIdx.x;
  int b = blk >> 4, c = blk & 15;
  __shared__ int gcur[NBK], lcnt[NBK], lfill[NBK];
  __shared__ int lbase[NBK + 1];
  __shared__ unsigned sbuf[2048];
  int tid = threadIdx.x;
  if (tid < NBK) gcur[tid] = cursor[(blk << 4) + tid];
  const int* srcp = ei + (size_t)b * 2 * E + c * 8192;
  const int* dstp = srcp + E;
  unsigned* pb = pbuf + (size_t)b * E;

  for (int sc = 0; sc < 4; ++sc) {
    if (tid < NBK) { lcnt[tid] = 0; lfill[tid] = 0; }
    __syncthreads();
    int s8[8], d8[8];
#pragma unroll
    for (int q = 0; q < 8; ++q) {
      int i = sc * 2048 + q * 256 + tid;
      s8[q] = srcp[i]; d8[q] = dstp[i];
      atomicAdd(&lcnt[d8[q] >> 9], 1);
    }
    __syncthreads();
    if (tid == 0) {
      int run = 0;
      for (int k = 0; k < NBK; ++k) { lbase[k] = run; run += lcnt[k]; }
      lbase[NBK] = run;
    }
    __syncthreads();
#pragma unroll
    for (int q = 0; q < 8; ++q) {
      int k = d8[q] >> 9;
      int idx = atomicAdd(&lfill[k], 1);
      sbuf[lbase[k] + idx] = ((unsigned)(d8[q] & 511) << 13) | (unsigned)s8[q];
    }
    __syncthreads();
    for (int i = tid; i < 2048; i += 256) {
      int k = 0;
      while (lbase[k + 1] <= i) ++k;
      pb[gcur[k] + (i - lbase[k])] = sbuf[i];
    }
    __syncthreads();
    if (tid < NBK) gcur[tid] += lcnt[tid];
    __syncthreads();
  }
}

__global__ __launch_bounds__(256) void final_scatter(const unsigned* __restrict__ pbuf,
                                                     const int* __restrict__ bbase,
                                                     int* __restrict__ csr,
                                                     int* __restrict__ offs,
                                                     float* __restrict__ dinv1) {
  int blk = blockIdx.x;
  int b = blk >> 4, k = blk & 15;
  __shared__ int ncnt[512], nbase[512], nfill[512];
  __shared__ int sred[256];
  __shared__ unsigned sbuf[FCAP];
  int tid = threadIdx.x;
  int gbase = bbase[b * (NBK + 1) + k];
  int gend  = bbase[b * (NBK + 1) + k + 1];
  int cnt = gend - gbase;
  const unsigned* pb = pbuf + (size_t)b * E + gbase;

  for (int i = tid; i < 512; i += 256) { ncnt[i] = 0; nfill[i] = 0; }
  __syncthreads();
  for (int i = tid; i < cnt; i += 256) atomicAdd(&ncnt[pb[i] >> 13], 1);
  __syncthreads();
  int v0 = ncnt[2 * tid], v1 = ncnt[2 * tid + 1];
  int s = v0 + v1;
  sred[tid] = s;
  __syncthreads();
  for (int off = 1; off < 256; off <<= 1) {
    int x = (tid >= off) ? sred[tid - off] : 0;
    __syncthreads();
    sred[tid] += x;
    __syncthreads();
  }
  int ex = sred[tid] - s;
  nbase[2 * tid] = ex;
  nbase[2 * tid + 1] = ex + v0;
  __syncthreads();
  for (int i = tid; i < 512; i += 256) {
    int node = k * 512 + i;
    offs[b * (N + 1) + node] = gbase + nbase[i];
    dinv1[b * N + node] = rsqrtf((float)ncnt[i] + 1.0f);
  }
  if (k == 15 && tid == 0) offs[b * (N + 1) + N] = E;
  __syncthreads();
  for (int i = tid; i < cnt; i += 256) {
    unsigned pk = pb[i];
    int node = pk >> 13;
    int idx = atomicAdd(&nfill[node], 1);
    sbuf[nbase[node] + idx] = pk & 8191u;
  }
  __syncthreads();
  int* co = csr + (size_t)b * E + gbase;
  for (int i = tid; i < cnt; i += 256) co[i] = (int)sbuf[i];
}

// ---------------------------------------------------------------------------
// W[128][128] fp32 -> Wt[128][128] bf16 transposed, 3 weights in one launch
// ---------------------------------------------------------------------------
__global__ __launch_bounds__(256) void prep_wt3(const float* __restrict__ W1,
                                                const float* __restrict__ W2,
                                                const float* __restrict__ W3,
                                                unsigned short* __restrict__ Wt) {
  const float* W = (blockIdx.x == 0) ? W1 : (blockIdx.x == 1) ? W2 : W3;
  unsigned short* o = Wt + blockIdx.x * 128 * 128;
  for (int i = threadIdx.x; i < 128 * 128; i += 256) {
    int k = i >> 7, n = i & 127;
    o[n * 128 + k] = f2bf(W[i]);
  }
}

// ---------------------------------------------------------------------------
// MFMA GEMM: C[M,128](bf16) = diag(fscale) @ A[M,128] @ W.
// fscale commutes through the GEMM -> applied to C rows in the epilogue
// (bf16 A path is now a pure uint4 copy).
// ---------------------------------------------------------------------------
template <bool ABF16>
__global__ __launch_bounds__(256) void gemm_mfma(const void* __restrict__ Ap,
                                                 const unsigned short* __restrict__ Wt,
                                                 unsigned short* __restrict__ Cb,
                                                 const float* __restrict__ fscale) {
  int wv   = threadIdx.x >> 6;
  int lane = threadIdx.x & 63;
  int l15  = lane & 15, lg = lane >> 4;
  size_t rowbase = (size_t)blockIdx.x * 128 + wv * 32;

  short8 afrag[2][4];
#pragma unroll
  for (int rg = 0; rg < 2; ++rg) {
    size_t row = rowbase + rg * 16 + l15;
#pragma unroll
    for (int c = 0; c < 4; ++c) {
      int k0 = c * 32 + lg * 8;
      if (ABF16) {
        afrag[rg][c] = *(const short8*)((const unsigned short*)Ap + row * 128 + k0);
      } else {
        const float* p = (const float*)Ap + row * 128 + k0;
        float4 v0 = *(const float4*)p;
        float4 v1 = *(const float4*)(p + 4);
        short8 a;
        a[0] = (short)f2bf(v0.x); a[1] = (short)f2bf(v0.y);
        a[2] = (short)f2bf(v0.z); a[3] = (short)f2bf(v0.w);
        a[4] = (short)f2bf(v1.x); a[5] = (short)f2bf(v1.y);
        a[6] = (short)f2bf(v1.z); a[7] = (short)f2bf(v1.w);
        afrag[rg][c] = a;
      }
    }
  }

  float fsr0[4] = {1.f, 1.f, 1.f, 1.f}, fsr1[4] = {1.f, 1.f, 1.f, 1.f};
  if (fscale != nullptr) {
    float4 t0 = *(const float4*)(fscale + rowbase + lg * 4);
    float4 t1 = *(const float4*)(fscale + rowbase + 16 + lg * 4);
    fsr0[0] = t0.x; fsr0[1] = t0.y; fsr0[2] = t0.z; fsr0[3] = t0.w;
    fsr1[0] = t1.x; fsr1[1] = t1.y; fsr1[2] = t1.z; fsr1[3] = t1.w;
  }

#pragma unroll
  for (int t = 0; t < 8; ++t) {
    int col = t * 16 + l15;
    short8 bfrag[4];
#pragma unroll
    for (int c = 0; c < 4; ++c)
      bfrag[c] = *(const short8*)(Wt + col * 128 + c * 32 + lg * 8);

    floatx4 acc0 = {0.f, 0.f, 0.f, 0.f};
    floatx4 acc1 = {0.f, 0.f, 0.f, 0.f};
#pragma unroll
    for (int c = 0; c < 4; ++c) {
      acc0 = __builtin_amdgcn_mfma_f32_16x16x32_bf16(afrag[0][c], bfrag[c], acc0, 0, 0, 0);
      acc1 = __builtin_amdgcn_mfma_f32_16x16x32_bf16(afrag[1][c], bfrag[c], acc1, 0, 0, 0);
    }
#pragma unroll
    for (int r = 0; r < 4; ++r) {
      size_t row0 = rowbase + lg * 4 + r;
      size_t row1 = rowbase + 16 + lg * 4 + r;
      Cb[row0 * 128 + col] = f2bf(acc0[r] * fsr0[r]);
      Cb[row1 * 128 + col] = f2bf(acc1[r] * fsr1[r]);
    }
  }
}

// ---------------------------------------------------------------------------
// GCN aggregation v4: wave per node, 4 edges per dwordx4 load.
// Lane group g=lane>>4 handles edge i+g; lane covers 16 B of the row.
// PACKED: edge list is (src<<16 | bf16(dinv[src])), live edges only.
// ---------------------------------------------------------------------------
template <bool PACKED>
__global__ __launch_bounds__(256) void gcn_agg4(
    const unsigned* __restrict__ tmp, const float* __restrict__ dinv,
    const int* __restrict__ offs, const unsigned* __restrict__ csrp,
    const float* __restrict__ bias, unsigned* __restrict__ hout,
    const float* __restrict__ wrel, const float* __restrict__ wroot,
    float* __restrict__ rr, float* __restrict__ tt) {
  int blk = blockIdx.x;
  int xcd = blk & 7;
  int j   = blk >> 3;                      // 0..4095
  int b   = xcd * 2 + (j >> 11);           // 2 graphs per XCD
  int n   = (j & 2047) * 4 + (threadIdx.x >> 6);
  int wid = b * N + n;
  int lane = threadIdx.x & 63;
  int g = lane >> 4;
  int fo = (lane & 15) << 4;               // byte offset within a 256 B row

  float dv = rdlane_f(dinv[wid], 0);
  uint4* hrow4 = (uint4*)(hout + (size_t)wid * 64);

  if (PACKED && dv <= 0.0f) {              // dead destination: zeros for readout
    if (lane < 16) hrow4[lane] = make_uint4(0u, 0u, 0u, 0u);
    return;
  }

  const char* tmpb = (const char*)(tmp + (((size_t)b << 13) << 6));
  const float* dvb = dinv + (b << 13);
  const unsigned* cp = csrp + (size_t)b * E;

  float acc[8] = {};

  int nbase = b * (N + 1) + n;
  int o0 = __builtin_amdgcn_readfirstlane(offs[nbase]);
  int o1 = __builtin_amdgcn_readfirstlane(offs[nbase + 1]);

  for (int base = o0; base < o1; base += 64) {
    int nv = o1 - base; if (nv > 64) nv = 64;
    int sl = 0; float wl = 0.0f;
    if (lane < nv) {
      unsigned v = cp[base + lane];
      if (PACKED) { sl = (int)(v >> 16); wl = bf2f((unsigned short)(v & 0xFFFFu)); }
      else        { sl = (int)v;         wl = dvb[sl]; }
    }
    for (int i0 = 0; i0 < nv; i0 += 16) {
      uint4 u[4]; float wq[4];
#pragma unroll
      for (int q = 0; q < 4; ++q) {
        if (i0 + q * 4 < nv) {             // wave-uniform
          int e = i0 + q * 4 + g;
          int   sq = __shfl(sl, e);
          wq[q]    = __shfl(wl, e);
          u[q] = *(const uint4*)(tmpb + (((unsigned)sq << 8) + fo));
        } else { wq[q] = 0.0f; u[q] = make_uint4(0u, 0u, 0u, 0u); }
      }
#pragma unroll
      for (int q = 0; q < 4; ++q) {
        acc[0] += wq[q] * __uint_as_float(u[q].x << 16);
        acc[1] += wq[q] * __uint_as_float(u[q].x & 0xFFFF0000u);
        acc[2] += wq[q] * __uint_as_float(u[q].y << 16);
        acc[3] += wq[q] * __uint_as_float(u[q].y & 0xFFFF0000u);
        acc[4] += wq[q] * __uint_as_float(u[q].z << 16);
        acc[5] += wq[q] * __uint_as_float(u[q].z & 0xFFFF0000u);
        acc[6] += wq[q] * __uint_as_float(u[q].w << 16);
        acc[7] += wq[q] * __uint_as_float(u[q].w & 0xFFFF0000u);
      }
    }
  }

  // reduce the 4 lane groups
#pragma unroll
  for (int q = 0; q < 8; ++q) {
    acc[q] += __shfl_xor(acc[q], 16);
    acc[q] += __shfl_xor(acc[q], 32);
  }

  // self term + bias + relu
  uint4 su = *(const uint4*)(tmpb + (((unsigned)n << 8) + fo));
  float sv[8];
  sv[0] = __uint_as_float(su.x << 16); sv[1] = __uint_as_float(su.x & 0xFFFF0000u);
  sv[2] = __uint_as_float(su.y << 16); sv[3] = __uint_as_float(su.y & 0xFFFF0000u);
  sv[4] = __uint_as_float(su.z << 16); sv[5] = __uint_as_float(su.z & 0xFFFF0000u);
  sv[6] = __uint_as_float(su.w << 16); sv[7] = __uint_as_float(su.w & 0xFFFF0000u);
  const float4 b0 = *(const float4*)(bias + (fo >> 1));
  const float4 b1 = *(const float4*)(bias + (fo >> 1) + 4);
  float outv[8];
  outv[0] = fmaxf(dv * (acc[0] + dv * sv[0]) + b0.x, 0.f);
  outv[1] = fmaxf(dv * (acc[1] + dv * sv[1]) + b0.y, 0.f);
  outv[2] = fmaxf(dv * (acc[2] + dv * sv[2]) + b0.z, 0.f);
  outv[3] = fmaxf(dv * (acc[3] + dv * sv[3]) + b0.w, 0.f);
  outv[4] = fmaxf(dv * (acc[4] + dv * sv[4]) + b1.x, 0.f);
  outv[5] = fmaxf(dv * (acc[5] + dv * sv[5]) + b1.y, 0.f);
  outv[6] = fmaxf(dv * (acc[6] + dv * sv[6]) + b1.z, 0.f);
  outv[7] = fmaxf(dv * (acc[7] + dv * sv[7]) + b1.w, 0.f);

  uint4 po;
  po.x = cvt_pk_bf16(outv[0], outv[1]);
  po.y = cvt_pk_bf16(outv[2], outv[3]);
  po.z = cvt_pk_bf16(outv[4], outv[5]);
  po.w = cvt_pk_bf16(outv[6], outv[7]);
  if (lane < 16) hrow4[lane] = po;

  if (rr != nullptr) {                      // fused pool dots r=h.wrel t=h.wroot
    const float4 wr0 = *(const float4*)(wrel + (fo >> 1));
    const float4 wr1 = *(const float4*)(wrel + (fo >> 1) + 4);
    const float4 wo0 = *(const float4*)(wroot + (fo >> 1));
    const float4 wo1 = *(const float4*)(wroot + (fo >> 1) + 4);
    float pr = outv[0] * wr0.x + outv[1] * wr0.y + outv[2] * wr0.z + outv[3] * wr0.w
             + outv[4] * wr1.x + outv[5] * wr1.y + outv[6] * wr1.z + outv[7] * wr1.w;
    float pt = outv[0] * wo0.x + outv[1] * wo0.y + outv[2] * wo0.z + outv[3] * wo0.w
             + outv[4] * wo1.x + outv[5] * wo1.y + outv[6] * wo1.z + outv[7] * wo1.w;
#pragma unroll
    for (int d = 1; d < 16; d <<= 1) {
      pr += __shfl_xor(pr, d);
      pt += __shfl_xor(pt, d);
    }
    if (lane == 0) { rr[wid] = pr; tt[wid] = pt; }
  }
}

// ---------------------------------------------------------------------------
// deg_count: live in-neighbor count under new mask + new dinv. 16 lanes/node.
// ---------------------------------------------------------------------------
template <bool PACKED>
__global__ __launch_bounds__(256) void deg_count(const float* __restrict__ mask,
                                                 const int* __restrict__ offs_in,
                                                 const unsigned* __restrict__ csr_in,
                                                 int* __restrict__ livecnt,
                                                 float* __restrict__ dinv_out) {
  int grp = threadIdx.x >> 4, gl = threadIdx.x & 15;
  int nid = blockIdx.x * 16 + grp;
  int b = nid >> 13, n = nid & (N - 1);
  float m = mask[nid];
  float s = 0.0f;
  if (m > 0.0f) {
    int o0 = offs_in[b * (N + 1) + n], o1 = offs_in[b * (N + 1) + n + 1];
    const unsigned* cs = csr_in + (size_t)b * E;
    const float* mb = mask + b * N;
    for (int base = o0; base < o1; base += 16)
      if (base + gl < o1) {
        unsigned v = cs[base + gl];
        int src = PACKED ? (int)(v >> 16) : (int)v;
        s += (mb[src] > 0.0f) ? 1.0f : 0.0f;
      }
  }
#pragma unroll
  for (int d = 8; d > 0; d >>= 1) s += __shfl_xor(s, d, 16);
  if (gl == 0) {
    bool live = (m > 0.0f);
    livecnt[nid] = live ? (int)s : 0;
    dinv_out[nid] = live ? rsqrtf(s + 1.0f) : 0.0f;
  }
}

// ---------------------------------------------------------------------------
// per-graph exclusive scan of livecnt -> offs_out (1024 thr, 8 elems each)
// ---------------------------------------------------------------------------
__global__ __launch_bounds__(1024) void scan_live(const int* __restrict__ cnt,
                                                  int* __restrict__ offs_out) {
  int b = blockIdx.x, t = threadIdx.x;
  __shared__ int sums[1024];
  int base = b * N + t * 8;
  int v[8]; int s = 0;
#pragma unroll
  for (int i = 0; i < 8; ++i) { v[i] = cnt[base + i]; s += v[i]; }
  sums[t] = s; __syncthreads();
  for (int off = 1; off < 1024; off <<= 1) {
    int x = (t >= off) ? sums[t - off] : 0;
    __syncthreads();
    sums[t] += x;
    __syncthreads();
  }
  int run = sums[t] - s;
#pragma unroll
  for (int i = 0; i < 8; ++i) {
    offs_out[b * (N + 1) + t * 8 + i] = run;
    run += v[i];
  }
  if (t == 1023) offs_out[b * (N + 1) + N] = run;
}

// ---------------------------------------------------------------------------
// compact: write packed live-edge list (src<<16 | bf16(dinv[src])).
// Wave per node; ballot-prefix keeps writes dense and sequential.
// ---------------------------------------------------------------------------
template <bool PACKED>
__global__ __launch_bounds__(256) void compact_csr(const int* __restrict__ offs_in,
                                                   const unsigned* __restrict__ csr_in,
                                                   const float* __restrict__ dinv_new,
                                                   const int* __restrict__ offs_out,
                                                   unsigned* __restrict__ csr_out) {
  int wid = blockIdx.x * 4 + (threadIdx.x >> 6);
  int lane = threadIdx.x & 63;
  int b = wid >> 13, n = wid & (N - 1);
  float dvn = rdlane_f(dinv_new[wid], 0);
  if (dvn <= 0.0f) return;                         // dead dst: empty range
  int o0 = __builtin_amdgcn_readfirstlane(offs_in[b * (N + 1) + n]);
  int o1 = __builtin_amdgcn_readfirstlane(offs_in[b * (N + 1) + n + 1]);
  int wbase = __builtin_amdgcn_readfirstlane(offs_out[b * (N + 1) + n]);
  const unsigned* cs = csr_in + (size_t)b * E;
  const float* dvb = dinv_new + (b << 13);
  unsigned* co = csr_out + (size_t)b * E;
  for (int base = o0; base < o1; base += 64) {
    int nv = o1 - base; if (nv > 64) nv = 64;
    int s = 0; float w = 0.0f;
    if (lane < nv) {
      unsigned v = cs[base + lane];
      s = PACKED ? (int)(v >> 16) : (int)v;
      w = dvb[s];
    }
    bool live = (lane < nv) && (w > 0.0f);
    unsigned long long bal = __ballot(live);
    int idx = __popcll(bal & ((1ull << lane) - 1ull));
    if (live) co[wbase + idx] = ((unsigned)s << 16) | (unsigned)f2bf(w);
    wbase += __popcll(bal);
  }
}

// ---------------------------------------------------------------------------
// pool score: score[n] = live*(sum_in r[src] + t[n] + b); 16 lanes/node.
// livep: null = all live; else >0 test (mask or dinv).
// ---------------------------------------------------------------------------
template <bool PACKED>
__global__ __launch_bounds__(256) void score_agg(const float* __restrict__ r,
                                                 const float* __restrict__ t,
                                                 const float* __restrict__ pb,
                                                 const float* __restrict__ livep,
                                                 const int* __restrict__ offs,
                                                 const unsigned* __restrict__ csrp,
                                                 float* __restrict__ score) {
  int grp = threadIdx.x >> 4;
  int gl  = threadIdx.x & 15;
  int nid = blockIdx.x * 16 + grp;
  int b = nid >> 13, n = nid & (N - 1);
  bool live = (livep == nullptr) || (livep[nid] > 0.0f);
  float s = 0.0f;
  if (live) {
    int o0 = offs[b * (N + 1) + n], o1 = offs[b * (N + 1) + n + 1];
    const unsigned* cs = csrp + (size_t)b * E;
    const float* rb = r + b * N;
    for (int base = o0; base < o1; base += 16)
      if (base + gl < o1) {
        unsigned v = cs[base + gl];
        s += rb[PACKED ? (v >> 16) : v];
      }
  }
#pragma unroll
  for (int d = 8; d > 0; d >>= 1) s += __shfl_xor(s, d, 16);
  if (gl == 0) score[nid] = live ? (s + t[nid] + pb[0]) : 0.0f;
}

// ---------------------------------------------------------------------------
// top-k via radix select (unchanged from R5)
// ---------------------------------------------------------------------------
__device__ __forceinline__ unsigned fkey(float s, float m) {
  if (m <= 0.0f) return 0u;
  unsigned u = __float_as_uint(s);
  return (u & 0x80000000u) ? ~u : (u | 0x80000000u);
}

__global__ __launch_bounds__(1024) void topk_kernel(const float* __restrict__ score,
                                                    const float* __restrict__ mkin,
                                                    float* __restrict__ mkout,
                                                    float* __restrict__ fscale,
                                                    int k) {
  int b = blockIdx.x, tid = threadIdx.x;
  const float* sc = score + b * N;
  float* mk = mkout + b * N;
  float* fs = fscale + b * N;
  __shared__ unsigned keyb[N];
  __shared__ int hist[256];
  __shared__ int sbuf[1024];
  __shared__ unsigned sh_prefix;
  __shared__ int sh_kneed;

  for (int i = tid; i < N; i += 1024) {
    float m = (mkin == nullptr) ? 1.0f : mkin[b * N + i];
    keyb[i] = fkey(sc[i], m);
  }
  __syncthreads();

  unsigned prefix = 0, hm = 0;
  int kneed = k;
  for (int shift = 24; shift >= 0; shift -= 8) {
    if (tid < 256) hist[tid] = 0;
    __syncthreads();
    for (int i = tid; i < N; i += 1024) {
      unsigned key = keyb[i];
      if ((key & hm) == prefix) atomicAdd(&hist[(key >> shift) & 255], 1);
    }
    __syncthreads();
    if (tid < 256) sbuf[tid] = hist[tid];
    __syncthreads();
    for (int off = 1; off < 256; off <<= 1) {
      int v = (tid < 256 && tid + off < 256) ? sbuf[tid + off] : 0;
      __syncthreads();
      if (tid < 256) sbuf[tid] += v;
      __syncthreads();
    }
    if (tid < 256) {
      int ge = sbuf[tid];
      int gt = (tid < 255) ? sbuf[tid + 1] : 0;
      if (ge >= kneed && gt < kneed) {
        sh_prefix = prefix | ((unsigned)tid << shift);
        sh_kneed = kneed - gt;
      }
    }
    __syncthreads();
    prefix = sh_prefix;
    kneed = sh_kneed;
    hm |= (0xFFu << shift);
    __syncthreads();
  }

  unsigned T = prefix;
  int base = tid * 8;
  unsigned keys[8];
  int eqf[8];
  int cnt = 0;
#pragma unroll
  for (int q = 0; q < 8; ++q) {
    keys[q] = keyb[base + q];
    eqf[q] = (keys[q] == T) ? 1 : 0;
    cnt += eqf[q];
  }
  sbuf[tid] = cnt; __syncthreads();
  for (int off = 1; off < 1024; off <<= 1) {
    int x = (tid >= off) ? sbuf[tid - off] : 0;
    __syncthreads();
    sbuf[tid] += x;
    __syncthreads();
  }
  int ex = sbuf[tid] - cnt;
#pragma unroll
  for (int q = 0; q < 8; ++q) {
    bool sel = (keys[q] > T) || (eqf[q] && (ex < kneed));
    ex += eqf[q];
    mk[base + q] = sel ? 1.0f : 0.0f;
    fs[base + q] = sel ? tanhf(sc[base + q]) : 0.0f;
  }
}

// ---------------------------------------------------------------------------
// readout partials (bf16 h) + head MLP + log_softmax
// ---------------------------------------------------------------------------
__global__ __launch_bounds__(256) void readout(const unsigned short* __restrict__ h,
                                               float* __restrict__ part) {
  int b = blockIdx.x, c = blockIdx.y;
  int tid = threadIdx.x;
  int f = tid & 127, half = tid >> 7;
  float acc = 0.0f;
  for (int n = c * 256 + half; n < (c + 1) * 256; n += 2)
    acc += bf2f(h[((size_t)b * N + n) * 128 + f]);
  __shared__ float red[256];
  red[tid] = acc; __syncthreads();
  if (half == 0) part[((size_t)b * 32 + c) * 128 + f] = red[f] + red[f + 128];
}

__global__ __launch_bounds__(128) void head(const float* __restrict__ part,
                                            const float* __restrict__ l1w,
                                            const float* __restrict__ l1b,
                                            const float* __restrict__ l2w,
                                            const float* __restrict__ l2b,
                                            float* __restrict__ out) {
  int b = blockIdx.x, f = threadIdx.x;
  float g = 0.0f;
  for (int c = 0; c < 32; ++c) g += part[((size_t)b * 32 + c) * 128 + f];
  g *= (1.0f / (float)K2);
  __shared__ float gs[128], hh[128], lg[10];
  gs[f] = g; __syncthreads();
  float a = l1b[f];
  for (int kk = 0; kk < 128; ++kk) a += gs[kk] * l1w[kk * 128 + f];
  hh[f] = fmaxf(a, 0.0f); __syncthreads();
  if (f < 10) {
    float l = l2b[f];
    for (int j = 0; j < 128; ++j) l += hh[j] * l2w[j * 10 + f];
    lg[f] = l;
  }
  __syncthreads();
  if (f == 0) {
    float m = lg[0];
    for (int c = 1; c < 10; ++c) m = fmaxf(m, lg[c]);
    float s = 0.0f;
    for (int c = 0; c < 10; ++c) s += expf(lg[c] - m);
    float lse = m + logf(s);
    for (int c = 0; c < 10; ++c) out[b * 10 + c] = lg[c] - lse;
  }
}

// ---------------------------------------------------------------------------
extern "C" void kernel_launch(void* const* d_in, const int* in_sizes, int n_in,
                              void* d_out, int out_size, void* d_ws, size_t ws_size,
                              hipStream_t stream) {
  (void)in_sizes; (void)n_in; (void)out_size; (void)ws_size;
  const float* x       = (const float*)d_in[0];
  const int*   ei      = (const int*)d_in[1];
  const float* W1      = (const float*)d_in[2];
  const float* b1      = (const float*)d_in[3];
  const float* p1_wrel = (const float*)d_in[4];
  const float* p1_wroot= (const float*)d_in[5];
  const float* p1_b    = (const float*)d_in[6];
  const float* W2      = (const float*)d_in[7];
  const float* b2      = (const float*)d_in[8];
  const float* p2_wrel = (const float*)d_in[9];
  const float* p2_wroot= (const float*)d_in[10];
  const float* p2_b    = (const float*)d_in[11];
  const float* W3      = (const float*)d_in[12];
  const float* b3      = (const float*)d_in[13];
  const float* l1w     = (const float*)d_in[14];
  const float* l1b     = (const float*)d_in[15];
  const float* l2w     = (const float*)d_in[16];
  const float* l2b     = (const float*)d_in[17];
  float* out = (float*)d_out;

  char* p = (char*)d_ws;
  auto alloc = [&](size_t bytes) {
    char* r = p;
    p += ((bytes + 255) & ~(size_t)255);
    return r;
  };
  unsigned short* h   = (unsigned short*)alloc((size_t)B * N * H * 2);   // bf16
  unsigned short* tmp = (unsigned short*)alloc((size_t)B * N * H * 2);   // bf16
  int*      offs   = (int*)alloc((size_t)B * (N + 1) * 4);
  int*      offs2  = (int*)alloc((size_t)B * (N + 1) * 4);
  int*      offs3  = (int*)alloc((size_t)B * (N + 1) * 4);
  int*      csr    = (int*)alloc((size_t)B * E * 4);
  unsigned* pbuf   = (unsigned*)alloc((size_t)B * E * 4);
  unsigned* csr2p  = (unsigned*)alloc((size_t)B * E * 4);
  unsigned* csr3p  = (unsigned*)alloc((size_t)B * E * 4);
  int*      bchist = (int*)alloc((size_t)B * CHUNKS * NBK * 4);
  int*      cursor = (int*)alloc((size_t)B * CHUNKS * NBK * 4);
  int*      bbase  = (int*)alloc((size_t)B * (NBK + 1) * 4);
  int*      livecnt= (int*)alloc((size_t)B * N * 4);
  float* dinv   = (float*)alloc((size_t)B * N * 4);
  float* mask   = (float*)alloc((size_t)B * N * 4);
  float* rr     = (float*)alloc((size_t)B * N * 4);
  float* tt     = (float*)alloc((size_t)B * N * 4);
  float* score  = (float*)alloc((size_t)B * N * 4);
  float* fscale = (float*)alloc((size_t)B * N * 4);
  float* part   = (float*)alloc((size_t)B * 32 * H * 4);
  unsigned short* Wts = (unsigned short*)alloc(3 * 128 * 128 * 2);

  // CSR build (streaming counting sort) + weight prep
  hist_pass<<<B * CHUNKS, 256, 0, stream>>>(ei, bchist);
  bucket_scan<<<B, 256, 0, stream>>>(bchist, cursor, bbase);
  bin_scatter<<<B * CHUNKS, 256, 0, stream>>>(ei, cursor, pbuf);
  final_scatter<<<B * NBK, 256, 0, stream>>>(pbuf, bbase, csr, offs, dinv);
  prep_wt3<<<3, 256, 0, stream>>>(W1, W2, W3, Wts);

  // ---- layer 1 + pool 1 (all nodes live)
  gemm_mfma<false><<<(B * N) / 128, 256, 0, stream>>>(x, Wts, tmp, nullptr);
  gcn_agg4<false><<<B * N / 4, 256, 0, stream>>>((const unsigned*)tmp, dinv, offs,
                                                 (const unsigned*)csr, b1, (unsigned*)h,
                                                 p1_wrel, p1_wroot, rr, tt);
  score_agg<false><<<B * N / 16, 256, 0, stream>>>(rr, tt, p1_b, nullptr, offs,
                                                   (const unsigned*)csr, score);
  topk_kernel<<<B, 1024, 0, stream>>>(score, nullptr, mask, fscale, K1);

  // ---- compact to live subgraph (mask1), layer 2 + pool 2
  deg_count<false><<<B * N / 16, 256, 0, stream>>>(mask, offs, (const unsigned*)csr,
                                                   livecnt, dinv);
  scan_live<<<B, 1024, 0, stream>>>(livecnt, offs2);
  compact_csr<false><<<B * N / 4, 256, 0, stream>>>(offs, (const unsigned*)csr, dinv,
                                                    offs2, csr2p);
  gemm_mfma<true><<<(B * N) / 128, 256, 0, stream>>>(h, Wts + 128 * 128, tmp, fscale);
  gcn_agg4<true><<<B * N / 4, 256, 0, stream>>>((const unsigned*)tmp, dinv, offs2,
                                                csr2p, b2, (unsigned*)h,
                                                p2_wrel, p2_wroot, rr, tt);
  score_agg<true><<<B * N / 16, 256, 0, stream>>>(rr, tt, p2_b, dinv, offs2, csr2p, score);
  topk_kernel<<<B, 1024, 0, stream>>>(score, mask, mask, fscale, K2);

  // ---- compact to live subgraph (mask2), layer 3
  deg_count<true><<<B * N / 16, 256, 0, stream>>>(mask, offs2, csr2p, livecnt, dinv);
  scan_live<<<B, 1024, 0, stream>>>(livecnt, offs3);
  compact_csr<true><<<B * N / 4, 256, 0, stream>>>(offs2, csr2p, dinv, offs3, csr3p);
  gemm_mfma<true><<<(B * N) / 128, 256, 0, stream>>>(h, Wts + 2 * 128 * 128, tmp, fscale);
  gcn_agg4<true><<<B * N / 4, 256, 0, stream>>>((const unsigned*)tmp, dinv, offs3,
                                                csr3p, b3, (unsigned*)h,
                                                nullptr, nullptr, nullptr, nullptr);

  // ---- readout + head
  readout<<<dim3(B, 32), 256, 0, stream>>>(h, part);
  head<<<B, 128, 0, stream>>>(part, l1w, l1b, l2w, l2b, out);
}